// Round 1
// baseline (15699.104 us; speedup 1.0000x reference)
//
#include <hip/hip_runtime.h>
#include <hip/hip_bf16.h>
#include <math.h>

// Problem constants (from reference)
#define S      610
#define E      126
#define BATCH  32
#define T      2048
#define NREG   5000

#define SPAD   640            // padded state dim (columns), multiple of 64
#define KB     80             // k-blocks of 8 states: 80*8 = 640 (zero-padded past 610)
#define FWD_THREADS 320       // 5 waves; each thread owns columns j and j+320

typedef _Float16 half2_t __attribute__((ext_vector_type(2)));

__device__ __forceinline__ float dot2f(unsigned int a, unsigned int b, float c) {
#if __has_builtin(__builtin_amdgcn_fdot2)
    return __builtin_amdgcn_fdot2(__builtin_bit_cast(half2_t, a),
                                  __builtin_bit_cast(half2_t, b), c, false);
#else
    half2_t x = __builtin_bit_cast(half2_t, a);
    half2_t y = __builtin_bit_cast(half2_t, b);
    return c + (float)x[0] * (float)y[0] + (float)x[1] * (float)y[1];
#endif
}

// Pack A (fp32 [S,S]) into fp16, layout A4[kb][j] = uint4 of 8 halves A[8kb+r][j],
// zero-padded so pad rows/cols contribute exactly 0 to dot products.
__global__ void k_packA(const float* __restrict__ A, uint4* __restrict__ A4) {
    int j  = threadIdx.x;   // 0..639
    int kb = blockIdx.x;    // 0..79
    unsigned short h[8];
#pragma unroll
    for (int r = 0; r < 8; ++r) {
        int i = kb * 8 + r;
        float v = (i < S && j < S) ? A[i * S + j] : 0.f;
        _Float16 hv = (_Float16)v;
        h[r] = __builtin_bit_cast(unsigned short, hv);
    }
    uint4 out;
    out.x = h[0] | ((unsigned)h[1] << 16);
    out.y = h[2] | ((unsigned)h[3] << 16);
    out.z = h[4] | ((unsigned)h[5] << 16);
    out.w = h[6] | ((unsigned)h[7] << 16);
    A4[kb * SPAD + j] = out;
}

// Transpose Bm [S,E] -> BmT [E][SPAD] fp32 so per-step emission loads are coalesced.
__global__ void k_bmt(const float* __restrict__ Bm, float* __restrict__ BmT) {
    int j = threadIdx.x;    // 0..639
    int o = blockIdx.x;     // 0..125
    BmT[o * SPAD + j] = (j < S) ? Bm[j * E + o] : 0.f;
}

// One-hot inputs -> integer observation symbols (exact: one_hot entries are 1.0f).
__global__ void k_obs(const float* __restrict__ in, int* __restrict__ obs) {
    int i = blockIdx.x * blockDim.x + threadIdx.x;
    if (i >= BATCH * T) return;
    const float2* p = (const float2*)(in + (size_t)i * E);  // 8B aligned: 126*4 = 504
    int o = 0;
#pragma unroll
    for (int k = 0; k < E / 2; ++k) {
        float2 v = p[k];
        if (v.x > 0.5f) o = 2 * k;
        if (v.y > 0.5f) o = 2 * k + 1;
    }
    obs[i] = o;
}

// Regularization: sum log1p(-A[f,t]) over the 5000 punished transitions (fp32 exact A).
__global__ void k_reg(const float* __restrict__ A, const int* __restrict__ rf,
                      const int* __restrict__ rt, float* __restrict__ out) {
    __shared__ float wpart[16];
    int tid = threadIdx.x;
    float s = 0.f;
    for (int i = tid; i < NREG; i += 1024)
        s += log1pf(-A[rf[i] * S + rt[i]]);
#pragma unroll
    for (int off = 1; off < 64; off <<= 1) s += __shfl_xor(s, off, 64);
    if ((tid & 63) == 0) wpart[tid >> 6] = s;
    __syncthreads();
    if (tid == 0) {
        float t = 0.f;
        for (int w = 0; w < 16; ++w) t += wpart[w];
        out[0] = t;
    }
}

// Persistent forward recursion: one block per batch element. alpha (normalized,
// fp16) lives in LDS; each step every thread computes 2 output states as
// fp16-dot2 columns against LDS-broadcast alpha pairs, then block-reduces z,
// accumulates log z, renormalizes.
__global__ __launch_bounds__(FWD_THREADS) void k_forward(
    const uint4* __restrict__ A4,   // [KB][SPAD]
    const float* __restrict__ BmT,  // [E][SPAD]
    const int* __restrict__ obs,    // [BATCH][T]
    const float* __restrict__ Iv,   // [S]
    double* __restrict__ ll_out)    // [BATCH]
{
    const int b = blockIdx.x;
    const int tid = threadIdx.x;
    const int j0 = tid, j1 = tid + FWD_THREADS;
    __shared__ __align__(16) _Float16 alpha[SPAD];
    __shared__ float wsum[FWD_THREADS / 64];
    const int* ob = obs + b * T;

    // t = 0: alpha0 = I * em0, z0, ll = log z0
    int o0 = ob[0];
    float a0 = (j0 < S ? Iv[j0] : 0.f) * BmT[o0 * SPAD + j0];
    float a1 = (j1 < S ? Iv[j1] : 0.f) * BmT[o0 * SPAD + j1];
    float v = a0 + a1;
#pragma unroll
    for (int off = 1; off < 64; off <<= 1) v += __shfl_xor(v, off, 64);
    if ((tid & 63) == 0) wsum[tid >> 6] = v;
    __syncthreads();
    float z = wsum[0] + wsum[1] + wsum[2] + wsum[3] + wsum[4];
    double ll = (double)logf(z);
    float inv = 1.f / z;
    alpha[j0] = (_Float16)(a0 * inv);
    alpha[j1] = (_Float16)(a1 * inv);
    __syncthreads();

    const uint4* al4 = (const uint4*)alpha;

    for (int t = 1; t < T; ++t) {
        int ot = ob[t];
        float e0 = BmT[ot * SPAD + j0];   // hoisted: overlaps with the k-loop
        float e1 = BmT[ot * SPAD + j1];
        float acc0 = 0.f, acc1 = 0.f;
        const uint4* Ap = A4 + j0;
#pragma unroll 8
        for (int kb = 0; kb < KB; ++kb) {
            uint4 w0 = Ap[(size_t)kb * SPAD];                // column j0, coalesced
            uint4 w1 = Ap[(size_t)kb * SPAD + FWD_THREADS];  // column j1, coalesced
            uint4 al = al4[kb];                              // LDS broadcast (16B)
            acc0 = dot2f(w0.x, al.x, acc0);
            acc0 = dot2f(w0.y, al.y, acc0);
            acc0 = dot2f(w0.z, al.z, acc0);
            acc0 = dot2f(w0.w, al.w, acc0);
            acc1 = dot2f(w1.x, al.x, acc1);
            acc1 = dot2f(w1.y, al.y, acc1);
            acc1 = dot2f(w1.z, al.z, acc1);
            acc1 = dot2f(w1.w, al.w, acc1);
        }
        acc0 *= e0; acc1 *= e1;
        v = acc0 + acc1;
#pragma unroll
        for (int off = 1; off < 64; off <<= 1) v += __shfl_xor(v, off, 64);
        if ((tid & 63) == 0) wsum[tid >> 6] = v;
        __syncthreads();   // also guarantees all alpha reads of this step are done
        z = wsum[0] + wsum[1] + wsum[2] + wsum[3] + wsum[4];
        ll += (double)logf(z);
        inv = 1.f / z;
        alpha[j0] = (_Float16)(acc0 * inv);
        alpha[j1] = (_Float16)(acc1 * inv);
        __syncthreads();   // writes visible before next step's reads / wsum reuse
    }
    if (tid == 0) ll_out[b] = ll;
}

__global__ void k_final(const double* __restrict__ ll, const float* __restrict__ regsum,
                        float* __restrict__ out) {
    double s = 0.0;
    for (int b = 0; b < BATCH; ++b) s += ll[b];
    double loglik_mean = s / BATCH;
    double reg_mean = (double)regsum[0] / NREG;
    out[0] = (float)(-loglik_mean - 4.0 * reg_mean);
}

extern "C" void kernel_launch(void* const* d_in, const int* in_sizes, int n_in,
                              void* d_out, int out_size, void* d_ws, size_t ws_size,
                              hipStream_t stream) {
    const float* inputs = (const float*)d_in[0];
    const float* A      = (const float*)d_in[1];
    const float* Bm     = (const float*)d_in[2];
    const float* Iv     = (const float*)d_in[3];
    const int*   rf     = (const int*)d_in[4];
    const int*   rt     = (const int*)d_in[5];

    // Workspace layout (recomputed every call; ws is re-poisoned by harness)
    char* ws = (char*)d_ws;
    uint4*  A4   = (uint4*)ws;                                   // 80*640*16  = 819200
    float*  BmT  = (float*)(ws + 819200);                        // 126*640*4  = 322560
    int*    obs  = (int*)(ws + 819200 + 322560);                 // 65536*4    = 262144
    double* ll   = (double*)(ws + 819200 + 322560 + 262144);     // 32*8       = 256
    float*  regs = (float*)(ws + 819200 + 322560 + 262144 + 256);

    hipLaunchKernelGGL(k_packA, dim3(KB), dim3(SPAD), 0, stream, A, A4);
    hipLaunchKernelGGL(k_bmt,   dim3(E),  dim3(SPAD), 0, stream, Bm, BmT);
    hipLaunchKernelGGL(k_obs,   dim3((BATCH * T + 255) / 256), dim3(256), 0, stream, inputs, obs);
    hipLaunchKernelGGL(k_reg,   dim3(1),  dim3(1024), 0, stream, A, rf, rt, regs);
    hipLaunchKernelGGL(k_forward, dim3(BATCH), dim3(FWD_THREADS), 0, stream, A4, BmT, obs, Iv, ll);
    hipLaunchKernelGGL(k_final, dim3(1), dim3(1), 0, stream, ll, regs, (float*)d_out);
}

// Round 2
// 12063.011 us; speedup vs baseline: 1.3014x; 1.3014x over previous
//
#include <hip/hip_runtime.h>
#include <math.h>

// Problem constants
#define S      610
#define E      126
#define BATCH  32
#define T      2048
#define NREG   5000

#define SPAD   640            // padded state dim, multiple of 64
#define KB16   40             // 40 k-blocks of 16 states: 40*16 = 640
#define FWD_THREADS 640       // 10 waves; one output column per thread

typedef float f32x2 __attribute__((ext_vector_type(2)));

// ---------- fp8 e4m3 helpers (HW path on gfx950; software fallback kept) ----
__device__ __forceinline__ float sw_e4m3_dec(unsigned b) {
    unsigned e = (b >> 3) & 0xF, m = b & 7;
    if (e == 0) return (float)m * 0.001953125f;            // m * 2^-9
    return __int_as_float((int)(((e + 120u) << 23) | (m << 20)));
}
__device__ __forceinline__ unsigned sw_e4m3_enc(float f) {
    if (!(f > 0.f)) return 0u;
    int e; float fr = frexpf(f, &e);                       // f = fr*2^e, fr in [0.5,1)
    if (e - 1 < -6) {                                      // denormal region
        int q = (int)rintf(f * 512.f);
        if (q > 7) q = 7;
        return (unsigned)q;
    }
    int m = (int)rintf(fr * 16.f) - 8;                     // 3-bit mantissa
    int EE = e - 1;
    if (m == 8) { m = 0; EE += 1; }
    if (EE > 8) { EE = 8; m = 7; }                         // clamp to 448
    return (unsigned)(((EE + 7) << 3) | m);
}

template <bool HI>
__device__ __forceinline__ f32x2 unpk(unsigned dw) {
#if __has_builtin(__builtin_amdgcn_cvt_pk_f32_fp8)
    return __builtin_amdgcn_cvt_pk_f32_fp8((int)dw, HI);
#else
    unsigned h = HI ? (dw >> 16) : (dw & 0xFFFFu);
    f32x2 r; r.x = sw_e4m3_dec(h & 0xFF); r.y = sw_e4m3_dec(h >> 8);
    return r;
#endif
}
__device__ __forceinline__ unsigned pack_quad(float v0, float v1, float v2, float v3) {
#if __has_builtin(__builtin_amdgcn_cvt_pk_fp8_f32)
    int w = 0;
    w = __builtin_amdgcn_cvt_pk_fp8_f32(v0, v1, w, false);
    w = __builtin_amdgcn_cvt_pk_fp8_f32(v2, v3, w, true);
    return (unsigned)w;
#else
    return sw_e4m3_enc(v0) | (sw_e4m3_enc(v1) << 8) |
           (sw_e4m3_enc(v2) << 16) | (sw_e4m3_enc(v3) << 24);
#endif
}

// ---------- prep kernels ----------------------------------------------------
__global__ void k_init(unsigned* __restrict__ maxbuf) { maxbuf[0] = 0u; }

// max over A (all entries positive -> uint compare == float compare)
__global__ void k_max(const float* __restrict__ A, unsigned* __restrict__ maxbuf) {
    int tid = blockIdx.x * blockDim.x + threadIdx.x;
    float m = 0.f;
    for (int i = tid; i < S * S; i += gridDim.x * blockDim.x) m = fmaxf(m, A[i]);
#pragma unroll
    for (int off = 1; off < 64; off <<= 1) m = fmaxf(m, __shfl_xor(m, off, 64));
    if ((threadIdx.x & 63) == 0) atomicMax(maxbuf, __float_as_uint(m));
}

__global__ void k_scalefin(const unsigned* __restrict__ maxbuf,
                           float* __restrict__ s_out, double* __restrict__ logs_out) {
    float mx = __uint_as_float(maxbuf[0]);
    float s = 224.f / mx;
    s_out[0] = s;
    logs_out[0] = log((double)s);
}

// Pack A*s into fp8: A8[kb][j] = uint4 of 16 bytes = rows 16kb..16kb+15, col j.
__global__ void k_pack8(const float* __restrict__ A, const float* __restrict__ s_in,
                        uint4* __restrict__ A8) {
    int j  = threadIdx.x;   // 0..639
    int kb = blockIdx.x;    // 0..39
    float s = s_in[0];
    unsigned dw[4];
#pragma unroll
    for (int g = 0; g < 4; ++g) {
        float v[4];
#pragma unroll
        for (int r = 0; r < 4; ++r) {
            int i = kb * 16 + g * 4 + r;
            v[r] = (i < S && j < S) ? A[i * S + j] * s : 0.f;
        }
        dw[g] = pack_quad(v[0], v[1], v[2], v[3]);
    }
    A8[kb * SPAD + j] = make_uint4(dw[0], dw[1], dw[2], dw[3]);
}

// Transpose Bm [S,E] -> BmT [E][SPAD] fp32 (coalesced per-step emission loads).
__global__ void k_bmt(const float* __restrict__ Bm, float* __restrict__ BmT) {
    int j = threadIdx.x;    // 0..639
    int o = blockIdx.x;     // 0..125
    BmT[o * SPAD + j] = (j < S) ? Bm[j * E + o] : 0.f;
}

// One-hot inputs -> observation symbols (exact).
__global__ void k_obs(const float* __restrict__ in, int* __restrict__ obs) {
    int i = blockIdx.x * blockDim.x + threadIdx.x;
    if (i >= BATCH * T) return;
    const float2* p = (const float2*)(in + (size_t)i * E);
    int o = 0;
#pragma unroll
    for (int k = 0; k < E / 2; ++k) {
        float2 v = p[k];
        if (v.x > 0.5f) o = 2 * k;
        if (v.y > 0.5f) o = 2 * k + 1;
    }
    obs[i] = o;
}

// Regularization on exact fp32 A.
__global__ void k_reg(const float* __restrict__ A, const int* __restrict__ rf,
                      const int* __restrict__ rt, float* __restrict__ out) {
    __shared__ float wpart[16];
    int tid = threadIdx.x;
    float s = 0.f;
    for (int i = tid; i < NREG; i += 1024)
        s += log1pf(-A[rf[i] * S + rt[i]]);
#pragma unroll
    for (int off = 1; off < 64; off <<= 1) s += __shfl_xor(s, off, 64);
    if ((tid & 63) == 0) wpart[tid >> 6] = s;
    __syncthreads();
    if (tid == 0) {
        float t = 0.f;
        for (int w = 0; w < 16; ++w) t += wpart[w];
        out[0] = t;
    }
}

// ---------- forward recursion ----------------------------------------------
// One block per batch element; 640 threads, one output column each.
// A streamed from L2 in fp8 (scaled by s); alpha fp32 in LDS; fp32 accumulate.
// ll corrected by -2047*log(s) at the end.
__global__ __launch_bounds__(FWD_THREADS) void k_forward(
    const uint4* __restrict__ A8,    // [KB16][SPAD]
    const float* __restrict__ BmT,   // [E][SPAD]
    const int*   __restrict__ obs,   // [BATCH][T]
    const float* __restrict__ Iv,    // [S]
    const double* __restrict__ logs, // log(s)
    double* __restrict__ ll_out)     // [BATCH]
{
    const int b = blockIdx.x;
    const int j = threadIdx.x;
    __shared__ __align__(16) float alpha[SPAD];
    __shared__ float wsum[FWD_THREADS / 64];
    const int* ob = obs + b * T;

    // t = 0 (unscaled: no A involved)
    int o0 = ob[0];
    float a0 = (j < S ? Iv[j] : 0.f) * BmT[o0 * SPAD + j];
    float v = a0;
#pragma unroll
    for (int off = 1; off < 64; off <<= 1) v += __shfl_xor(v, off, 64);
    if ((j & 63) == 0) wsum[j >> 6] = v;
    __syncthreads();
    float z = 0.f;
#pragma unroll
    for (int w = 0; w < FWD_THREADS / 64; ++w) z += wsum[w];
    double ll = (double)logf(z);
    alpha[j] = a0 * (1.f / z);
    __syncthreads();

    const uint4* Ap = A8 + j;
    const float4* al4 = (const float4*)alpha;

    for (int t = 1; t < T; ++t) {
        int ot = ob[t];
        float ej = BmT[ot * SPAD + j];          // hoisted, overlaps k-loop
        float acc0 = 0.f, acc1 = 0.f;
#pragma unroll 4
        for (int kb = 0; kb < KB16; ++kb) {
            uint4 w = Ap[(size_t)kb * SPAD];    // 16 fp8 of column j, coalesced
            float4 q0 = al4[kb * 4 + 0];        // 16 alpha values, LDS broadcast
            float4 q1 = al4[kb * 4 + 1];
            float4 q2 = al4[kb * 4 + 2];
            float4 q3 = al4[kb * 4 + 3];
            f32x2 p;
            p = unpk<false>(w.x); acc0 = fmaf(p.x, q0.x, acc0); acc1 = fmaf(p.y, q0.y, acc1);
            p = unpk<true >(w.x); acc0 = fmaf(p.x, q0.z, acc0); acc1 = fmaf(p.y, q0.w, acc1);
            p = unpk<false>(w.y); acc0 = fmaf(p.x, q1.x, acc0); acc1 = fmaf(p.y, q1.y, acc1);
            p = unpk<true >(w.y); acc0 = fmaf(p.x, q1.z, acc0); acc1 = fmaf(p.y, q1.w, acc1);
            p = unpk<false>(w.z); acc0 = fmaf(p.x, q2.x, acc0); acc1 = fmaf(p.y, q2.y, acc1);
            p = unpk<true >(w.z); acc0 = fmaf(p.x, q2.z, acc0); acc1 = fmaf(p.y, q2.w, acc1);
            p = unpk<false>(w.w); acc0 = fmaf(p.x, q3.x, acc0); acc1 = fmaf(p.y, q3.y, acc1);
            p = unpk<true >(w.w); acc0 = fmaf(p.x, q3.z, acc0); acc1 = fmaf(p.y, q3.w, acc1);
        }
        float acc = (acc0 + acc1) * ej;
        v = acc;
#pragma unroll
        for (int off = 1; off < 64; off <<= 1) v += __shfl_xor(v, off, 64);
        if ((j & 63) == 0) wsum[j >> 6] = v;
        __syncthreads();                        // wsum visible; alpha reads done
        z = 0.f;
#pragma unroll
        for (int w = 0; w < FWD_THREADS / 64; ++w) z += wsum[w];
        ll += (double)logf(z);
        alpha[j] = acc * (1.f / z);
        __syncthreads();                        // alpha visible for next step
    }
    if (j == 0) ll_out[b] = ll - 2047.0 * logs[0];
}

__global__ void k_final(const double* __restrict__ ll, const float* __restrict__ regsum,
                        float* __restrict__ out) {
    double s = 0.0;
    for (int b = 0; b < BATCH; ++b) s += ll[b];
    double loglik_mean = s / BATCH;
    double reg_mean = (double)regsum[0] / NREG;
    out[0] = (float)(-loglik_mean - 4.0 * reg_mean);
}

// ---------- launch ----------------------------------------------------------
extern "C" void kernel_launch(void* const* d_in, const int* in_sizes, int n_in,
                              void* d_out, int out_size, void* d_ws, size_t ws_size,
                              hipStream_t stream) {
    const float* inputs = (const float*)d_in[0];
    const float* A      = (const float*)d_in[1];
    const float* Bm     = (const float*)d_in[2];
    const float* Iv     = (const float*)d_in[3];
    const int*   rf     = (const int*)d_in[4];
    const int*   rt     = (const int*)d_in[5];

    char* ws = (char*)d_ws;
    uint4*    A8   = (uint4*)ws;                         // 40*640*16 = 409600
    float*    BmT  = (float*)(ws + 409600);              // 126*640*4 = 322560
    int*      obs  = (int*)(ws + 732160);                // 65536*4   = 262144
    double*   ll   = (double*)(ws + 994304);             // 32*8      = 256
    float*    regs = (float*)(ws + 994560);              // 4
    unsigned* mx   = (unsigned*)(ws + 994564);           // 4
    float*    sbuf = (float*)(ws + 994568);              // 4
    double*   logs = (double*)(ws + 994576);             // 8 (8-aligned)

    hipLaunchKernelGGL(k_init,     dim3(1),   dim3(1),   0, stream, mx);
    hipLaunchKernelGGL(k_max,      dim3(256), dim3(256), 0, stream, A, mx);
    hipLaunchKernelGGL(k_scalefin, dim3(1),   dim3(1),   0, stream, mx, sbuf, logs);
    hipLaunchKernelGGL(k_pack8,    dim3(KB16), dim3(SPAD), 0, stream, A, sbuf, A8);
    hipLaunchKernelGGL(k_bmt,      dim3(E),   dim3(SPAD), 0, stream, Bm, BmT);
    hipLaunchKernelGGL(k_obs,      dim3((BATCH * T + 255) / 256), dim3(256), 0, stream, inputs, obs);
    hipLaunchKernelGGL(k_reg,      dim3(1),   dim3(1024), 0, stream, A, rf, rt, regs);
    hipLaunchKernelGGL(k_forward,  dim3(BATCH), dim3(FWD_THREADS), 0, stream,
                       A8, BmT, obs, Iv, logs, ll);
    hipLaunchKernelGGL(k_final,    dim3(1),   dim3(1),   0, stream, ll, regs, (float*)d_out);
}

// Round 3
// 10331.218 us; speedup vs baseline: 1.5196x; 1.1676x over previous
//
#include <hip/hip_runtime.h>
#include <math.h>

// Problem constants
#define S      610
#define E      126
#define BATCH  32
#define T      2048
#define NREG   5000

#define SPAD   640            // padded state dim
#define NT     40             // N-tiles of 16 columns
#define KCP    10             // K-chunk PAIRS (64 rows each; 2 MFMAs of K=32 per pair)
#define NB     8              // forward blocks
#define MB     4              // batches per block
#define THREADS 640           // 10 waves
#define TPW    4              // N-tiles per wave
#define PIN_NT 15             // N-tiles pinned in LDS (15*10240 = 153600 B)
#define AROW   656            // alphaq padded row stride (bank-conflict-free)

typedef float f32x4 __attribute__((ext_vector_type(4)));

// ---------- fp8 e4m3 encode (HW on gfx950, sw fallback) ---------------------
__device__ __forceinline__ unsigned sw_e4m3_enc(float f) {
    if (!(f > 0.f)) return 0u;
    int e; float fr = frexpf(f, &e);
    if (e - 1 < -6) {
        int q = (int)rintf(f * 512.f);
        if (q > 7) q = 7;
        return (unsigned)q;
    }
    int m = (int)rintf(fr * 16.f) - 8;
    int EE = e - 1;
    if (m == 8) { m = 0; EE += 1; }
    if (EE > 8) { EE = 8; m = 7; }
    return (unsigned)(((EE + 7) << 3) | m);
}
__device__ __forceinline__ unsigned pack_quad(float v0, float v1, float v2, float v3) {
#if __has_builtin(__builtin_amdgcn_cvt_pk_fp8_f32)
    int w = 0;
    w = __builtin_amdgcn_cvt_pk_fp8_f32(v0, v1, w, false);
    w = __builtin_amdgcn_cvt_pk_fp8_f32(v2, v3, w, true);
    return (unsigned)w;
#else
    return sw_e4m3_enc(v0) | (sw_e4m3_enc(v1) << 8) |
           (sw_e4m3_enc(v2) << 16) | (sw_e4m3_enc(v3) << 24);
#endif
}
__device__ __forceinline__ unsigned char fp8byte(float v) {
#if __has_builtin(__builtin_amdgcn_cvt_pk_fp8_f32)
    int w = __builtin_amdgcn_cvt_pk_fp8_f32(v, v, 0, false);
    return (unsigned char)(w & 0xFF);
#else
    return (unsigned char)sw_e4m3_enc(v);
#endif
}

// ---------- prep kernels ----------------------------------------------------
__global__ void k_init(unsigned* __restrict__ maxbuf) { maxbuf[0] = 0u; }

__global__ void k_max(const float* __restrict__ A, unsigned* __restrict__ maxbuf) {
    int tid = blockIdx.x * blockDim.x + threadIdx.x;
    float m = 0.f;
    for (int i = tid; i < S * S; i += gridDim.x * blockDim.x) m = fmaxf(m, A[i]);
#pragma unroll
    for (int off = 1; off < 64; off <<= 1) m = fmaxf(m, __shfl_xor(m, off, 64));
    if ((threadIdx.x & 63) == 0) atomicMax(maxbuf, __float_as_uint(m));
}

__global__ void k_scalefin(const unsigned* __restrict__ maxbuf,
                           float* __restrict__ s_out, double* __restrict__ logs_out) {
    float mx = __uint_as_float(maxbuf[0]);
    float s = 224.f / mx;
    s_out[0] = s;
    logs_out[0] = log((double)s);
}

// Pack A*s into fp8 in MFMA B-fragment order.
// Flat uint4 index (n*KCP + kcp)*64 + lane holds, for lane l:
//   col j = n*16 + (l&15);  bytes i=0..7 of .x/.y: k = kcp*64 + (l>>4)*8 + i
//                           bytes i=0..7 of .z/.w: k = kcp*64 + 32 + (l>>4)*8 + i
__global__ void k_pack8frag(const float* __restrict__ A, const float* __restrict__ s_in,
                            uint4* __restrict__ A8) {
    int n   = blockIdx.x;    // 0..NT-1
    int kcp = blockIdx.y;    // 0..KCP-1
    int l   = threadIdx.x;   // 0..63
    float s = s_in[0];
    int j  = n * 16 + (l & 15);
    int kq = (l >> 4) * 8;
    float v[16];
#pragma unroll
    for (int h = 0; h < 2; ++h)
#pragma unroll
        for (int i = 0; i < 8; ++i) {
            int k = kcp * 64 + h * 32 + kq + i;
            v[h * 8 + i] = (k < S && j < S) ? A[k * S + j] * s : 0.f;
        }
    uint4 out;
    out.x = pack_quad(v[0],  v[1],  v[2],  v[3]);
    out.y = pack_quad(v[4],  v[5],  v[6],  v[7]);
    out.z = pack_quad(v[8],  v[9],  v[10], v[11]);
    out.w = pack_quad(v[12], v[13], v[14], v[15]);
    A8[(n * KCP + kcp) * 64 + l] = out;
}

// Transpose Bm [S,E] -> BmT [E][SPAD] fp32.
__global__ void k_bmt(const float* __restrict__ Bm, float* __restrict__ BmT) {
    int j = threadIdx.x;
    int o = blockIdx.x;
    BmT[o * SPAD + j] = (j < S) ? Bm[j * E + o] : 0.f;
}

// One-hot inputs -> observation symbols (exact).
__global__ void k_obs(const float* __restrict__ in, int* __restrict__ obs) {
    int i = blockIdx.x * blockDim.x + threadIdx.x;
    if (i >= BATCH * T) return;
    const float2* p = (const float2*)(in + (size_t)i * E);
    int o = 0;
#pragma unroll
    for (int k = 0; k < E / 2; ++k) {
        float2 v = p[k];
        if (v.x > 0.5f) o = 2 * k;
        if (v.y > 0.5f) o = 2 * k + 1;
    }
    obs[i] = o;
}

// Regularization on exact fp32 A.
__global__ void k_reg(const float* __restrict__ A, const int* __restrict__ rf,
                      const int* __restrict__ rt, float* __restrict__ out) {
    __shared__ float wpart[16];
    int tid = threadIdx.x;
    float s = 0.f;
    for (int i = tid; i < NREG; i += 1024)
        s += log1pf(-A[rf[i] * S + rt[i]]);
#pragma unroll
    for (int off = 1; off < 64; off <<= 1) s += __shfl_xor(s, off, 64);
    if ((tid & 63) == 0) wpart[tid >> 6] = s;
    __syncthreads();
    if (tid == 0) {
        float t = 0.f;
        for (int w = 0; w < 16; ++w) t += wpart[w];
        out[0] = t;
    }
}

// ---------- forward recursion (MFMA fp8) ------------------------------------
// 8 blocks x 4 batches. C[m][j] = sum_k alphaq[m][k] * A8[k][j] via
// mfma_f32_16x16x32_fp8_fp8 (alpha = A-operand scaled x128; Amat = B-operand
// scaled x s). 15/40 N-tiles of A8 pinned in LDS; rest streamed from L2.
__global__ __launch_bounds__(THREADS, 1) void k_forward(
    const uint4* __restrict__ A8,
    const float* __restrict__ BmT,
    const int*   __restrict__ obs,
    const float* __restrict__ Iv,
    const double* __restrict__ logs,
    double* __restrict__ ll_out)
{
    __shared__ __align__(16) unsigned char pinA[PIN_NT * KCP * 64 * 16]; // 153600
    __shared__ __align__(16) unsigned char alphaq[MB * AROW];            // 2624
    __shared__ __align__(16) float zpart[(THREADS / 64) * 4];            // 160
    __shared__ float zsc[4];

    const int tid  = threadIdx.x;
    const int wv   = tid >> 6;
    const int lane = tid & 63;
    const int mrow = lane & 15;
    const int quad = lane >> 4;
    const int b0   = blockIdx.x * MB;
    const int n0   = wv * TPW;

    // Copy pinned A tiles into LDS (completion covered by t=0 barriers).
    {
        const uint4* src = A8;
        uint4* dst = (uint4*)pinA;
        for (int i = tid; i < PIN_NT * KCP * 64; i += THREADS) dst[i] = src[i];
    }

    // ---- t = 0: alpha0 = I * em0 (exact fp32), then quantize x128 ----------
    int ot[MB];
#pragma unroll
    for (int m = 0; m < MB; ++m) ot[m] = obs[(b0 + m) * T];
    float Ij = (tid < S) ? Iv[tid] : 0.f;
    float v0[MB], p0[MB];
#pragma unroll
    for (int m = 0; m < MB; ++m) { v0[m] = Ij * BmT[ot[m] * SPAD + tid]; p0[m] = v0[m]; }
#pragma unroll
    for (int off = 1; off < 64; off <<= 1)
#pragma unroll
        for (int m = 0; m < MB; ++m) p0[m] += __shfl_xor(p0[m], off, 64);
    if (lane == 0) {
#pragma unroll
        for (int m = 0; m < MB; ++m) zpart[wv * 4 + m] = p0[m];
    }
    __syncthreads();
    double ll = 0.0;
    if (tid < 4) {
        float z = 0.f;
        for (int w = 0; w < THREADS / 64; ++w) z += zpart[w * 4 + tid];
        ll = (double)logf(z);
        zsc[tid] = 128.f / z;
    }
    __syncthreads();
#pragma unroll
    for (int m = 0; m < MB; ++m)
        alphaq[m * AROW + tid] = fp8byte(v0[m] * zsc[m]);
    __syncthreads();

    const unsigned char* aq = alphaq + mrow * AROW + quad * 8;

    // ---- main recursion ----------------------------------------------------
    for (int t = 1; t < T; ++t) {
#pragma unroll
        for (int m = 0; m < MB; ++m) ot[m] = obs[(b0 + m) * T + t];

        // emission values for this wave's columns (lanes 0..15 hold C rows 0..3)
        float em[TPW][MB];
        if (lane < 16) {
#pragma unroll
            for (int tl = 0; tl < TPW; ++tl)
#pragma unroll
                for (int m = 0; m < MB; ++m)
                    em[tl][m] = BmT[ot[m] * SPAD + (n0 + tl) * 16 + lane];
        }

        // alpha A-operand fragments (rows 4..15 of the 16x16 tile are zero)
        long long af[2 * KCP];
#pragma unroll
        for (int kc = 0; kc < 2 * KCP; ++kc) af[kc] = 0;
        if (mrow < 4) {
#pragma unroll
            for (int kc = 0; kc < 2 * KCP; ++kc)
                af[kc] = *(const long long*)(aq + kc * 32);
        }

        // MFMA over this wave's 4 N-tiles
        f32x4 acc[TPW];
#pragma unroll
        for (int tl = 0; tl < TPW; ++tl) acc[tl] = (f32x4)0.f;
#pragma unroll
        for (int tl = 0; tl < TPW; ++tl) {
            const int n = n0 + tl;
            const uint4* bp = (n < PIN_NT)
                ? ((const uint4*)pinA) + (n * KCP) * 64 + lane
                : A8 + (n * KCP) * 64 + lane;
#pragma unroll
            for (int kp = 0; kp < KCP; ++kp) {
                uint4 w = bp[kp * 64];
                union { uint2 u; long long l; } c0, c1;
                c0.u = make_uint2(w.x, w.y);
                c1.u = make_uint2(w.z, w.w);
                acc[tl] = __builtin_amdgcn_mfma_f32_16x16x32_fp8_fp8(af[2 * kp],     c0.l, acc[tl], 0, 0, 0);
                acc[tl] = __builtin_amdgcn_mfma_f32_16x16x32_fp8_fp8(af[2 * kp + 1], c1.l, acc[tl], 0, 0, 0);
            }
        }

        // partial z per batch row (C layout: col = lane&15, row = reg for lanes<16)
        float pz[MB];
#pragma unroll
        for (int m = 0; m < MB; ++m) pz[m] = 0.f;
        if (lane < 16) {
#pragma unroll
            for (int tl = 0; tl < TPW; ++tl)
#pragma unroll
                for (int m = 0; m < MB; ++m)
                    pz[m] += acc[tl][m] * em[tl][m];
        }
#pragma unroll
        for (int off = 1; off < 16; off <<= 1)
#pragma unroll
            for (int m = 0; m < MB; ++m) pz[m] += __shfl_xor(pz[m], off, 64);
        if (lane == 0) {
#pragma unroll
            for (int m = 0; m < MB; ++m) zpart[wv * 4 + m] = pz[m];
        }
        __syncthreads();                      // zpart ready; all alphaq reads done
        if (tid < 4) {
            float z = 0.f;
            for (int w = 0; w < THREADS / 64; ++w) z += zpart[w * 4 + tid];
            ll += (double)logf(z);
            zsc[tid] = 128.f / z;
        }
        __syncthreads();                      // zsc ready; safe to overwrite alphaq
        if (lane < 16) {
#pragma unroll
            for (int tl = 0; tl < TPW; ++tl) {
                const int j = (n0 + tl) * 16 + lane;
#pragma unroll
                for (int m = 0; m < MB; ++m)
                    alphaq[m * AROW + j] = fp8byte(acc[tl][m] * em[tl][m] * zsc[m]);
            }
        }
        __syncthreads();                      // alphaq ready for next step
    }

    // per-step scale correction: each of 2047 steps carried factor 128*s
    const double LOG128 = 4.852030263919617;
    if (tid < 4) ll_out[b0 + tid] = ll - 2047.0 * (logs[0] + LOG128);
}

__global__ void k_final(const double* __restrict__ ll, const float* __restrict__ regsum,
                        float* __restrict__ out) {
    double s = 0.0;
    for (int b = 0; b < BATCH; ++b) s += ll[b];
    double loglik_mean = s / BATCH;
    double reg_mean = (double)regsum[0] / NREG;
    out[0] = (float)(-loglik_mean - 4.0 * reg_mean);
}

// ---------- launch ----------------------------------------------------------
extern "C" void kernel_launch(void* const* d_in, const int* in_sizes, int n_in,
                              void* d_out, int out_size, void* d_ws, size_t ws_size,
                              hipStream_t stream) {
    const float* inputs = (const float*)d_in[0];
    const float* A      = (const float*)d_in[1];
    const float* Bm     = (const float*)d_in[2];
    const float* Iv     = (const float*)d_in[3];
    const int*   rf     = (const int*)d_in[4];
    const int*   rt     = (const int*)d_in[5];

    char* ws = (char*)d_ws;
    uint4*    A8   = (uint4*)ws;                         // 40*10*64*16 = 409600
    float*    BmT  = (float*)(ws + 409600);              // 126*640*4   = 322560
    int*      obs  = (int*)(ws + 732160);                // 65536*4     = 262144
    double*   ll   = (double*)(ws + 994304);             // 32*8        = 256
    float*    regs = (float*)(ws + 994560);              // 4
    unsigned* mx   = (unsigned*)(ws + 994564);           // 4
    float*    sbuf = (float*)(ws + 994568);              // 4
    double*   logs = (double*)(ws + 994576);             // 8

    hipLaunchKernelGGL(k_init,      dim3(1),   dim3(1),   0, stream, mx);
    hipLaunchKernelGGL(k_max,       dim3(256), dim3(256), 0, stream, A, mx);
    hipLaunchKernelGGL(k_scalefin,  dim3(1),   dim3(1),   0, stream, mx, sbuf, logs);
    hipLaunchKernelGGL(k_pack8frag, dim3(NT, KCP), dim3(64), 0, stream, A, sbuf, A8);
    hipLaunchKernelGGL(k_bmt,       dim3(E),   dim3(SPAD), 0, stream, Bm, BmT);
    hipLaunchKernelGGL(k_obs,       dim3((BATCH * T + 255) / 256), dim3(256), 0, stream, inputs, obs);
    hipLaunchKernelGGL(k_reg,       dim3(1),   dim3(1024), 0, stream, A, rf, rt, regs);
    hipLaunchKernelGGL(k_forward,   dim3(NB),  dim3(THREADS), 0, stream,
                       A8, BmT, obs, Iv, logs, ll);
    hipLaunchKernelGGL(k_final,     dim3(1),   dim3(1),   0, stream, ll, regs, (float*)d_out);
}

// Round 4
// 8882.912 us; speedup vs baseline: 1.7673x; 1.1630x over previous
//
#include <hip/hip_runtime.h>
#include <math.h>

// Problem constants
#define S      610
#define E      126
#define BATCH  32
#define T      2048
#define NREG   5000

#define SPAD   640            // padded state dim
#define NT     40             // N-tiles of 16 columns (whole A)
#define KCP    10             // K-chunk pairs (64 rows each; 2 K=32 MFMAs per pair)
#define GROUPS 8              // batch groups
#define PARTS  4              // blocks per group (N-split)
#define NTB    10             // N-tiles per part (NT / PARTS)
#define MB     4              // batches per group
#define THREADS 640           // 10 waves; 1 N-tile per wave
#define AROW   656            // alphaq padded row stride
#define FLAGSTRIDE 16         // ints per flag (64 B padding)

typedef float f32x4 __attribute__((ext_vector_type(4)));

// ---------- fp8 e4m3 encode (HW on gfx950, sw fallback) ---------------------
__device__ __forceinline__ unsigned sw_e4m3_enc(float f) {
    if (!(f > 0.f)) return 0u;
    int e; float fr = frexpf(f, &e);
    if (e - 1 < -6) {
        int q = (int)rintf(f * 512.f);
        if (q > 7) q = 7;
        return (unsigned)q;
    }
    int m = (int)rintf(fr * 16.f) - 8;
    int EE = e - 1;
    if (m == 8) { m = 0; EE += 1; }
    if (EE > 8) { EE = 8; m = 7; }
    return (unsigned)(((EE + 7) << 3) | m);
}
__device__ __forceinline__ unsigned pack_quad(float v0, float v1, float v2, float v3) {
#if __has_builtin(__builtin_amdgcn_cvt_pk_fp8_f32)
    int w = 0;
    w = __builtin_amdgcn_cvt_pk_fp8_f32(v0, v1, w, false);
    w = __builtin_amdgcn_cvt_pk_fp8_f32(v2, v3, w, true);
    return (unsigned)w;
#else
    return sw_e4m3_enc(v0) | (sw_e4m3_enc(v1) << 8) |
           (sw_e4m3_enc(v2) << 16) | (sw_e4m3_enc(v3) << 24);
#endif
}
__device__ __forceinline__ unsigned char fp8byte(float v) {
#if __has_builtin(__builtin_amdgcn_cvt_pk_fp8_f32)
    int w = __builtin_amdgcn_cvt_pk_fp8_f32(v, v, 0, false);
    return (unsigned char)(w & 0xFF);
#else
    return (unsigned char)sw_e4m3_enc(v);
#endif
}

// ---------- prep kernels ----------------------------------------------------
__global__ void k_init(unsigned* __restrict__ maxbuf, int* __restrict__ seq) {
    maxbuf[0] = 0u;
    if (threadIdx.x < GROUPS * PARTS) seq[threadIdx.x * FLAGSTRIDE] = 0;
}

__global__ void k_max(const float* __restrict__ A, unsigned* __restrict__ maxbuf) {
    int tid = blockIdx.x * blockDim.x + threadIdx.x;
    float m = 0.f;
    for (int i = tid; i < S * S; i += gridDim.x * blockDim.x) m = fmaxf(m, A[i]);
#pragma unroll
    for (int off = 1; off < 64; off <<= 1) m = fmaxf(m, __shfl_xor(m, off, 64));
    if ((threadIdx.x & 63) == 0) atomicMax(maxbuf, __float_as_uint(m));
}

__global__ void k_scalefin(const unsigned* __restrict__ maxbuf,
                           float* __restrict__ s_out, double* __restrict__ logs_out) {
    float mx = __uint_as_float(maxbuf[0]);
    float s = 224.f / mx;
    s_out[0] = s;
    logs_out[0] = log((double)s);
}

// Pack A*s into fp8 in MFMA B-fragment order (layout verified in round 3).
__global__ void k_pack8frag(const float* __restrict__ A, const float* __restrict__ s_in,
                            uint4* __restrict__ A8) {
    int n   = blockIdx.x;    // 0..NT-1
    int kcp = blockIdx.y;    // 0..KCP-1
    int l   = threadIdx.x;   // 0..63
    float s = s_in[0];
    int j  = n * 16 + (l & 15);
    int kq = (l >> 4) * 8;
    float v[16];
#pragma unroll
    for (int h = 0; h < 2; ++h)
#pragma unroll
        for (int i = 0; i < 8; ++i) {
            int k = kcp * 64 + h * 32 + kq + i;
            v[h * 8 + i] = (k < S && j < S) ? A[k * S + j] * s : 0.f;
        }
    uint4 out;
    out.x = pack_quad(v[0],  v[1],  v[2],  v[3]);
    out.y = pack_quad(v[4],  v[5],  v[6],  v[7]);
    out.z = pack_quad(v[8],  v[9],  v[10], v[11]);
    out.w = pack_quad(v[12], v[13], v[14], v[15]);
    A8[(n * KCP + kcp) * 64 + l] = out;
}

__global__ void k_bmt(const float* __restrict__ Bm, float* __restrict__ BmT) {
    int j = threadIdx.x;
    int o = blockIdx.x;
    BmT[o * SPAD + j] = (j < S) ? Bm[j * E + o] : 0.f;
}

__global__ void k_obs(const float* __restrict__ in, int* __restrict__ obs) {
    int i = blockIdx.x * blockDim.x + threadIdx.x;
    if (i >= BATCH * T) return;
    const float2* p = (const float2*)(in + (size_t)i * E);
    int o = 0;
#pragma unroll
    for (int k = 0; k < E / 2; ++k) {
        float2 v = p[k];
        if (v.x > 0.5f) o = 2 * k;
        if (v.y > 0.5f) o = 2 * k + 1;
    }
    obs[i] = o;
}

__global__ void k_reg(const float* __restrict__ A, const int* __restrict__ rf,
                      const int* __restrict__ rt, float* __restrict__ out) {
    __shared__ float wpart[16];
    int tid = threadIdx.x;
    float s = 0.f;
    for (int i = tid; i < NREG; i += 1024)
        s += log1pf(-A[rf[i] * S + rt[i]]);
#pragma unroll
    for (int off = 1; off < 64; off <<= 1) s += __shfl_xor(s, off, 64);
    if ((tid & 63) == 0) wpart[tid >> 6] = s;
    __syncthreads();
    if (tid == 0) {
        float t = 0.f;
        for (int w = 0; w < 16; ++w) t += wpart[w];
        out[0] = t;
    }
}

// ---------- forward recursion: 8 groups x 4-way N-split ----------------------
// Block (g,p) owns columns [p*160, p*160+160); its A-slice lives entirely in
// LDS. Per step: MFMA from LDS -> publish c*em fp32 -> flag(release,agent) ->
// spin partners -> read full 640 -> z -> quantize alpha into LDS.
__global__ __launch_bounds__(THREADS, 1) void k_forward(
    const uint4* __restrict__ A8,
    const float* __restrict__ BmT,
    const int*   __restrict__ obs,
    const float* __restrict__ Iv,
    const double* __restrict__ logs,
    float* __restrict__ pub,        // [GROUPS][2][MB][SPAD] fp32
    int*   __restrict__ seq,        // [GROUPS*PARTS] stride FLAGSTRIDE
    double* __restrict__ ll_out)
{
    __shared__ __align__(16) unsigned char pinA[NTB * KCP * 64 * 16];  // 102400
    __shared__ __align__(16) unsigned char alphaq[MB * AROW];          // 2624
    __shared__ __align__(16) float zpart[(THREADS / 64) * MB];         // 160
    __shared__ float zsc[MB];

    const int g    = blockIdx.x & 7;
    const int p    = blockIdx.x >> 3;
    const int tid  = threadIdx.x;
    const int wv   = tid >> 6;
    const int lane = tid & 63;
    const int mrow = lane & 15;
    const int quad = lane >> 4;
    const int b0   = g * MB;
    const int jj   = (p * NTB + wv) * 16;   // this wave's global column base

    // Pin this part's A-slice in LDS (done before first use via t=0 barriers).
    {
        const uint4* src = A8 + (size_t)p * NTB * KCP * 64;
        uint4* dst = (uint4*)pinA;
        for (int i = tid; i < NTB * KCP * 64; i += THREADS) dst[i] = src[i];
    }

    // ---- t = 0: full alpha0 computed locally by every block -----------------
    int ot[MB];
#pragma unroll
    for (int m = 0; m < MB; ++m) ot[m] = obs[(b0 + m) * T];
    float Ij = (tid < S) ? Iv[tid] : 0.f;
    float v0[MB], p0[MB];
#pragma unroll
    for (int m = 0; m < MB; ++m) { v0[m] = Ij * BmT[ot[m] * SPAD + tid]; p0[m] = v0[m]; }
#pragma unroll
    for (int off = 1; off < 64; off <<= 1)
#pragma unroll
        for (int m = 0; m < MB; ++m) p0[m] += __shfl_xor(p0[m], off, 64);
    if (lane == 0) {
#pragma unroll
        for (int m = 0; m < MB; ++m) zpart[wv * MB + m] = p0[m];
    }
    __syncthreads();
    double ll = 0.0;
    if (tid < MB) {
        float z = 0.f;
        for (int w = 0; w < THREADS / 64; ++w) z += zpart[w * MB + tid];
        ll = (double)logf(z);
        zsc[tid] = 128.f / z;
    }
    __syncthreads();
#pragma unroll
    for (int m = 0; m < MB; ++m)
        alphaq[m * AROW + tid] = fp8byte(v0[m] * zsc[m]);
    __syncthreads();

    const unsigned char* aq = alphaq + mrow * AROW + quad * 8;
    const uint4* pin = ((const uint4*)pinA) + wv * KCP * 64 + lane;
    int* myflag = seq + (g * PARTS + p) * FLAGSTRIDE;

    // ---- main recursion -----------------------------------------------------
    for (int t = 1; t < T; ++t) {
#pragma unroll
        for (int m = 0; m < MB; ++m) ot[m] = obs[(b0 + m) * T + t];
        float em[MB];
        if (lane < 16) {
#pragma unroll
            for (int m = 0; m < MB; ++m) em[m] = BmT[ot[m] * SPAD + jj + mrow];
        }

        // alpha A-operand fragments (rows 4..15 zero)
        long long af[2 * KCP];
#pragma unroll
        for (int kc = 0; kc < 2 * KCP; ++kc) af[kc] = 0;
        if (mrow < 4) {
#pragma unroll
            for (int kc = 0; kc < 2 * KCP; ++kc)
                af[kc] = *(const long long*)(aq + kc * 32);
        }

        // 20 MFMAs on this wave's tile, 2 independent chains
        f32x4 acc0 = (f32x4)0.f, acc1 = (f32x4)0.f;
#pragma unroll
        for (int kp = 0; kp < KCP; ++kp) {
            uint4 w = pin[kp * 64];
            union { uint2 u; long long l; } c0, c1;
            c0.u = make_uint2(w.x, w.y);
            c1.u = make_uint2(w.z, w.w);
            if (kp & 1) {
                acc1 = __builtin_amdgcn_mfma_f32_16x16x32_fp8_fp8(af[2 * kp],     c0.l, acc1, 0, 0, 0);
                acc1 = __builtin_amdgcn_mfma_f32_16x16x32_fp8_fp8(af[2 * kp + 1], c1.l, acc1, 0, 0, 0);
            } else {
                acc0 = __builtin_amdgcn_mfma_f32_16x16x32_fp8_fp8(af[2 * kp],     c0.l, acc0, 0, 0, 0);
                acc0 = __builtin_amdgcn_mfma_f32_16x16x32_fp8_fp8(af[2 * kp + 1], c1.l, acc0, 0, 0, 0);
            }
        }

        // publish c*em for our 160 columns
        float* pt = pub + ((size_t)(g * 2 + (t & 1))) * (MB * SPAD);
        if (lane < 16) {
#pragma unroll
            for (int m = 0; m < MB; ++m)
                pt[m * SPAD + jj + mrow] = (acc0[m] + acc1[m]) * em[m];
        }
        __syncthreads();                       // all publishes issued
        if (tid == 0) {                        // set flag AFTER fence (separate if:
            __threadfence();                   //  reconverges before spin below)
            __hip_atomic_store(myflag, t, __ATOMIC_RELEASE, __HIP_MEMORY_SCOPE_AGENT);
        }
        if (tid < PARTS - 1) {                 // 3 threads spin on 3 partners
            int prt = (p + 1 + tid) & (PARTS - 1);
            const int* f = seq + (g * PARTS + prt) * FLAGSTRIDE;
            while (__hip_atomic_load(f, __ATOMIC_ACQUIRE, __HIP_MEMORY_SCOPE_AGENT) < t) {
                __builtin_amdgcn_s_sleep(1);
            }
        }
        __syncthreads();                       // everyone sees all parts published

        // read full 640-vector, reduce z, quantize
        float v[MB];
#pragma unroll
        for (int m = 0; m < MB; ++m) v[m] = pt[m * SPAD + tid];
        float pz[MB];
#pragma unroll
        for (int m = 0; m < MB; ++m) pz[m] = v[m];
#pragma unroll
        for (int off = 1; off < 64; off <<= 1)
#pragma unroll
            for (int m = 0; m < MB; ++m) pz[m] += __shfl_xor(pz[m], off, 64);
        if (lane == 0) {
#pragma unroll
            for (int m = 0; m < MB; ++m) zpart[wv * MB + m] = pz[m];
        }
        __syncthreads();
        if (tid < MB) {
            float z = 0.f;
            for (int w = 0; w < THREADS / 64; ++w) z += zpart[w * MB + tid];
            ll += (double)logf(z);
            zsc[tid] = 128.f / z;
        }
        __syncthreads();
#pragma unroll
        for (int m = 0; m < MB; ++m)
            alphaq[m * AROW + tid] = fp8byte(v[m] * zsc[m]);
        __syncthreads();                       // alphaq ready for next step
    }

    // every step's MFMA carried factor 128*s (publish was raw MFMA*em units)
    const double LOG128 = 4.852030263919617;
    if (p == 0 && tid < MB) ll_out[b0 + tid] = ll - 2047.0 * (logs[0] + LOG128);
}

__global__ void k_final(const double* __restrict__ ll, const float* __restrict__ regsum,
                        float* __restrict__ out) {
    double s = 0.0;
    for (int b = 0; b < BATCH; ++b) s += ll[b];
    double loglik_mean = s / BATCH;
    double reg_mean = (double)regsum[0] / NREG;
    out[0] = (float)(-loglik_mean - 4.0 * reg_mean);
}

// ---------- launch ----------------------------------------------------------
extern "C" void kernel_launch(void* const* d_in, const int* in_sizes, int n_in,
                              void* d_out, int out_size, void* d_ws, size_t ws_size,
                              hipStream_t stream) {
    const float* inputs = (const float*)d_in[0];
    const float* A      = (const float*)d_in[1];
    const float* Bm     = (const float*)d_in[2];
    const float* Iv     = (const float*)d_in[3];
    const int*   rf     = (const int*)d_in[4];
    const int*   rt     = (const int*)d_in[5];

    char* ws = (char*)d_ws;
    uint4*    A8   = (uint4*)ws;                         // 409600
    float*    BmT  = (float*)(ws + 409600);              // 322560
    int*      obs  = (int*)(ws + 732160);                // 262144
    double*   ll   = (double*)(ws + 994304);             // 256
    float*    regs = (float*)(ws + 994560);
    unsigned* mx   = (unsigned*)(ws + 994564);
    float*    sbuf = (float*)(ws + 994568);
    double*   logs = (double*)(ws + 994576);             // ..994584
    float*    pub  = (float*)(ws + 994816);              // 8*2*4*640*4 = 163840
    int*      seq  = (int*)(ws + 994816 + 163840);       // 32*64 = 2048

    hipLaunchKernelGGL(k_init,      dim3(1),   dim3(64),  0, stream, mx, seq);
    hipLaunchKernelGGL(k_max,       dim3(256), dim3(256), 0, stream, A, mx);
    hipLaunchKernelGGL(k_scalefin,  dim3(1),   dim3(1),   0, stream, mx, sbuf, logs);
    hipLaunchKernelGGL(k_pack8frag, dim3(NT, KCP), dim3(64), 0, stream, A, sbuf, A8);
    hipLaunchKernelGGL(k_bmt,       dim3(E),   dim3(SPAD), 0, stream, Bm, BmT);
    hipLaunchKernelGGL(k_obs,       dim3((BATCH * T + 255) / 256), dim3(256), 0, stream, inputs, obs);
    hipLaunchKernelGGL(k_reg,       dim3(1),   dim3(1024), 0, stream, A, rf, rt, regs);
    hipLaunchKernelGGL(k_forward,   dim3(GROUPS * PARTS), dim3(THREADS), 0, stream,
                       A8, BmT, obs, Iv, logs, pub, seq, ll);
    hipLaunchKernelGGL(k_final,     dim3(1),   dim3(1),   0, stream, ll, regs, (float*)d_out);
}